// Round 13
// baseline (355.048 us; speedup 1.0000x reference)
//
#include <hip/hip_runtime.h>
#include <math.h>

typedef unsigned int uint_t;
typedef __attribute__((ext_vector_type(8))) short bf16x8;
typedef __attribute__((ext_vector_type(4))) float f32x4;

#define BK_SHIFT 7
#define BK_NODES 128
#define MAXBK 512          // supports N <= 65536
#define PART_CHUNK 4096
#define SLAB 4096          // per-bucket slab capacity (lambda~2200, 40 sigma headroom)

__device__ __forceinline__ float lrelu(float x){ return x > 0.f ? x : 0.2f*x; }
__device__ __forceinline__ float wsum(float v){
    #pragma unroll
    for (int m = 1; m < 64; m <<= 1) v += __shfl_xor(v, m);
    return v;
}
__device__ __forceinline__ uint_t pack_bf2(float a, float b){
    uint_t ua = __float_as_uint(a); uint_t ub = __float_as_uint(b);
    ua += 0x7FFFu + ((ua >> 16) & 1u);
    ub += 0x7FFFu + ((ub >> 16) & 1u);
    return (ua >> 16) | (ub & 0xFFFF0000u);
}
__device__ __forceinline__ float bflo(uint_t u){ return __uint_as_float(u << 16); }
__device__ __forceinline__ float bfhi(uint_t u){ return __uint_as_float(u & 0xFFFF0000u); }
__device__ __forceinline__ bf16x8 mk_bf8(uint4 u){
    bf16x8 r;
    r[0]=(short)(u.x & 0xFFFFu); r[1]=(short)(u.x >> 16);
    r[2]=(short)(u.y & 0xFFFFu); r[3]=(short)(u.y >> 16);
    r[4]=(short)(u.z & 0xFFFFu); r[5]=(short)(u.z >> 16);
    r[6]=(short)(u.w & 0xFFFFu); r[7]=(short)(u.w >> 16);
    return r;
}

// ---------------- W pre-pack + gcursor zero (launched FIRST) ----------------
__global__ __launch_bounds__(256) void wpack_zero(
        const float* __restrict__ W2, const float* __restrict__ W3,
        uint_t* __restrict__ B2, uint_t* __restrict__ B3,
        int* __restrict__ gcursor){
    int idx = blockIdx.x * 256 + threadIdx.x;      // 0..16383
    if (idx < MAXBK) gcursor[idx] = 0;
    const float* W = (idx < 8192) ? W2 : W3;
    uint_t* Bp = (idx < 8192) ? B2 : B3;
    int i = idx & 8191;
    int u = i & 3, c = (i >> 2) & 15, kg = (i >> 6) & 3, kb = (i >> 8) & 3, cb = (i >> 10) & 7;
    int k = kb * 32 + kg * 8 + 2 * u;
    int col = cb * 16 + c;
    Bp[i] = pack_bf2(W[k * 128 + col], W[(k + 1) * 128 + col]);
}

// ---------------- CSR build (slab) ----------------

__global__ __launch_bounds__(256) void partition_slab(
        const int* __restrict__ ei, int E, int N,
        int* __restrict__ gcursor, uint_t* __restrict__ pairbuf, int NBK){
    __shared__ int hist[MAXBK];
    __shared__ int sA[MAXBK];
    __shared__ int destadj[MAXBK];
    __shared__ int cnt2[MAXBK];
    __shared__ uint_t staged[PART_CHUNK];
    __shared__ unsigned short sbk[PART_CHUNK];
    int t = threadIdx.x;
    int base = blockIdx.x * PART_CHUNK;
    int total = E + N;
    int cnt = total - base; if (cnt > PART_CHUNK) cnt = PART_CHUNK; if (cnt < 0) cnt = 0;

    int sreg[16], dreg[16];
    #pragma unroll
    for (int q = 0; q < 16; ++q){
        int i = t + q * 256;
        int idx = base + i;
        int s = 0, d = -1;
        if (i < cnt){
            if (idx < E){ s = ei[idx]; d = ei[E + idx]; }
            else        { s = d = idx - E; }
        }
        sreg[q] = s; dreg[q] = d;
    }

    for (int i = t; i < MAXBK; i += 256){ hist[i] = 0; cnt2[i] = 0; }
    __syncthreads();
    #pragma unroll
    for (int q = 0; q < 16; ++q)
        if (dreg[q] >= 0) atomicAdd(&hist[dreg[q] >> BK_SHIFT], 1);
    __syncthreads();
    sA[t] = hist[t]; sA[t + 256] = hist[t + 256];
    __syncthreads();
    for (int off = 1; off < MAXBK; off <<= 1){
        int i0 = t, i1 = t + 256;
        int a0 = sA[i0] + ((i0 >= off) ? sA[i0 - off] : 0);
        int a1 = sA[i1] + ((i1 >= off) ? sA[i1 - off] : 0);
        __syncthreads();
        sA[i0] = a0; sA[i1] = a1;
        __syncthreads();
    }
    for (int b = t; b < NBK; b += 256){
        int c = hist[b];
        int gstart = (b == 0) ? 0 : sA[b - 1];
        int rbase = c > 0 ? atomicAdd(&gcursor[b], c) : 0;
        destadj[b] = b * SLAB + rbase - gstart;
        cnt2[b] = gstart;
    }
    __syncthreads();
    #pragma unroll
    for (int q = 0; q < 16; ++q){
        if (dreg[q] >= 0){
            int b = dreg[q] >> BK_SHIFT;
            int pos = atomicAdd(&cnt2[b], 1);
            staged[pos] = (uint_t)sreg[q] | ((uint_t)(dreg[q] & (BK_NODES - 1)) << 25);
            sbk[pos] = (unsigned short)b;
        }
    }
    __syncthreads();
    for (int p = t; p < cnt; p += 256){
        int b = (int)sbk[p];
        pairbuf[destadj[b] + p] = staged[p];
    }
}

__global__ __launch_bounds__(256) void sort2_slab(
        const uint_t* __restrict__ pairbuf, const int* __restrict__ gcursor,
        int* __restrict__ indptr, int* __restrict__ indend,
        int* __restrict__ srcs, int N, int NBK){
    int b = blockIdx.x;
    int cnt = gcursor[b];
    int base = b * SLAB;
    int nb = b << BK_SHIFT;
    __shared__ int nh[BK_NODES];
    __shared__ int noff[BK_NODES];
    __shared__ int outb[SLAB];
    int t = threadIdx.x;
    if (t < BK_NODES) nh[t] = 0;
    __syncthreads();
    for (int i = t; i < cnt; i += 256){
        uint_t pr = pairbuf[base + i];
        atomicAdd(&nh[(int)(pr >> 25)], 1);
    }
    __syncthreads();
    if (t < BK_NODES) noff[t] = nh[t];
    __syncthreads();
    for (int off = 1; off < BK_NODES; off <<= 1){
        int u = 0;
        if (t < BK_NODES && t >= off) u = noff[t - off];
        __syncthreads();
        if (t < BK_NODES) noff[t] += u;
        __syncthreads();
    }
    if (t < BK_NODES){
        int node = nb + t;
        if (node < N){
            int excl = noff[t] - nh[t];
            indptr[node] = base + excl;
            indend[node] = base + noff[t];
        }
        nh[t] = noff[t] - nh[t];      // reuse as local cursor
    }
    __syncthreads();
    for (int i = t; i < cnt; i += 256){
        uint_t pr = pairbuf[base + i];
        int pos = atomicAdd(&nh[(int)(pr >> 25)], 1);
        outb[pos] = (int)(pr & 0x1FFFFFFu);
    }
    __syncthreads();
    for (int i = t; i < cnt; i += 256) srcs[base + i] = outb[i];
}

// ---------------- layer-1 linear (K=3): xp packed bf16x2 ----------------
__global__ __launch_bounds__(128) void linear_al(
        const float* __restrict__ in, const float* __restrict__ W,
        const float* __restrict__ as_, const float* __restrict__ ad_,
        uint_t* __restrict__ xp16, float* __restrict__ als, float* __restrict__ ald,
        int N, int K){
    __shared__ float hs[8 * 3];
    int t = threadIdx.x;
    int base = blockIdx.x * 8;
    int rows = N - base; if (rows > 8) rows = 8;
    for (int idx = t; idx < rows * K; idx += 128){
        int r = idx / K, k = idx - r * K;
        hs[r * K + k] = in[(size_t)(base + r) * K + k];
    }
    __syncthreads();
    float acc[8] = {0.f,0.f,0.f,0.f,0.f,0.f,0.f,0.f};
    for (int k = 0; k < K; ++k){
        float w = W[k * 128 + t];
        #pragma unroll
        for (int r = 0; r < 8; ++r) acc[r] += hs[r * K + k] * w;
    }
    float asv = as_[t], adv = ad_[t];
    for (int r = 0; r < rows; ++r){
        int row = base + r;
        float v = acc[r];
        float vo = __shfl_xor(v, 1);
        if (!(t & 1)) xp16[(size_t)row * 64 + (t >> 1)] = pack_bf2(v, vo);
        float vs = v * asv, vd = v * adv;
        #pragma unroll
        for (int m = 16; m >= 1; m >>= 1){
            vs += __shfl_xor(vs, m);
            vd += __shfl_xor(vd, m);
        }
        if ((t & 31) == 0){
            int h = t >> 5;
            als[row * 4 + h] = vs;
            ald[row * 4 + h] = vd;
        }
    }
}

// ---------------- K=128 linear via MFMA bf16; B staged in LDS per block ----------------
__global__ __launch_bounds__(256) void gemm_mfma(
        const uint_t* __restrict__ h16, const uint_t* __restrict__ bpack,
        const float* __restrict__ as_, const float* __restrict__ ad_,
        uint_t* __restrict__ xp16, float* __restrict__ als, float* __restrict__ ald,
        int N){
    __shared__ uint4 Bs[2048];         // 32 KB: full B-fragment table, shared by 4 waves
    int t = threadIdx.x;
    const uint4* bp4 = (const uint4*)bpack;
    #pragma unroll
    for (int q = 0; q < 8; ++q) Bs[t + q * 256] = bp4[t + q * 256];
    __syncthreads();                   // single barrier, before any early-return

    int w = threadIdx.x >> 6;
    int l = threadIdx.x & 63;
    int stripe = blockIdx.x * 4 + w;
    int base = stripe * 16;
    if (base >= N) return;
    int r16 = l & 15;
    int kg  = l >> 4;
    int row = base + r16;
    int rowc = row < N ? row : N - 1;

    bf16x8 afr[4];
    const uint4* hrow = (const uint4*)(h16 + (size_t)rowc * 64);
    #pragma unroll
    for (int kb = 0; kb < 4; ++kb) afr[kb] = mk_bf8(hrow[kb * 4 + kg]);

    f32x4 acc[8];
    #pragma unroll
    for (int cb = 0; cb < 8; ++cb) acc[cb] = (f32x4){0.f, 0.f, 0.f, 0.f};

    #pragma unroll
    for (int cb = 0; cb < 8; ++cb){
        #pragma unroll
        for (int kb = 0; kb < 4; ++kb){
            bf16x8 bfr = mk_bf8(Bs[((cb * 4 + kb) * 4 + kg) * 16 + r16]);
            acc[cb] = __builtin_amdgcn_mfma_f32_16x16x32_bf16(afr[kb], bfr, acc[cb], 0, 0, 0);
        }
    }

    #pragma unroll
    for (int reg = 0; reg < 4; ++reg){
        int ro = base + kg * 4 + reg;
        bool wr = (ro < N) && ((r16 & 1) == 0);
        #pragma unroll
        for (int cb = 0; cb < 8; ++cb){
            float v  = acc[cb][reg];
            float vo = __shfl_xor(v, 1);
            if (wr) xp16[(size_t)ro * 64 + cb * 8 + (r16 >> 1)] = pack_bf2(v, vo);
        }
        #pragma unroll
        for (int h = 0; h < 4; ++h){
            float a0 = as_[h * 32 + r16],      a1 = as_[h * 32 + 16 + r16];
            float g0 = ad_[h * 32 + r16],      g1 = ad_[h * 32 + 16 + r16];
            float ps = acc[2 * h][reg] * a0 + acc[2 * h + 1][reg] * a1;
            float pd = acc[2 * h][reg] * g0 + acc[2 * h + 1][reg] * g1;
            ps += __shfl_xor(ps, 1); ps += __shfl_xor(ps, 2);
            ps += __shfl_xor(ps, 4); ps += __shfl_xor(ps, 8);
            pd += __shfl_xor(pd, 1); pd += __shfl_xor(pd, 2);
            pd += __shfl_xor(pd, 4); pd += __shfl_xor(pd, 8);
            if (r16 == 0 && ro < N){
                als[(size_t)ro * 4 + h] = ps;
                ald[(size_t)ro * 4 + h] = pd;
            }
        }
    }
}

// ---------------- head-split aggregation: 16 lanes per (node, head) ----------------
// block -> head = (bid&7)>>1 (pins head h to XCDs {2h,2h+1} under round-robin
// blockIdx->XCD dispatch), chunk = (bid>>3)*2 + (bid&1). Per-head XP slice is
// 3.2 MB (one 64B line per row) -> fits a 4 MB XCD L2. Register staging +
// __shfl broadcast; no LDS, no barriers.
__global__ __launch_bounds__(256, 8) void gat_agg5(
        const uint_t* __restrict__ xp16, const float* __restrict__ als,
        const float* __restrict__ ald,
        const int* __restrict__ indptr, const int* __restrict__ indend,
        const int* __restrict__ srcs, const float* __restrict__ bias,
        uint_t* __restrict__ hout, int N){
    int bid = blockIdx.x;
    int h     = (bid & 7) >> 1;
    int chunk = (bid >> 3) * 2 + (bid & 1);
    int wid  = threadIdx.x >> 6;
    int lane = threadIdx.x & 63;
    int g = lane >> 4, l16 = lane & 15;
    int n = chunk * 16 + wid * 4 + g;
    if (n >= N) return;

    int beg = indptr[n], end = indend[n];
    float adh = ald[n * 4 + h];
    float d = 0.f, ax = 0.f, ay = 0.f;
    int gbase = g * 16;

    for (int cbeg = beg; cbeg < end; cbeg += 16){
        int cnt = end - cbeg; if (cnt > 16) cnt = 16;
        int s = 0; float w = 0.f;
        if (l16 < cnt){
            s = __builtin_nontemporal_load(&srcs[cbeg + l16]);
            w = __expf(lrelu(als[s * 4 + h] + adh));
            d += w;
        }
        #pragma unroll
        for (int e = 0; e < 16; ++e){
            int   se = __shfl(s, gbase + e);
            float we = __shfl(w, gbase + e);
            if (e < cnt){
                uint_t u = xp16[(size_t)se * 64 + h * 16 + l16];
                ax = fmaf(bflo(u), we, ax);
                ay = fmaf(bfhi(u), we, ay);
            }
        }
    }

    d += __shfl_xor(d, 1); d += __shfl_xor(d, 2);
    d += __shfl_xor(d, 4); d += __shfl_xor(d, 8);
    float inv = 1.f / (d + 1e-16f);
    float2 b2 = ((const float2*)bias)[h * 16 + l16];
    float vx = ax * inv + b2.x;
    float vy = ay * inv + b2.y;
    vx = vx > 0.f ? vx : (__expf(vx) - 1.f);
    vy = vy > 0.f ? vy : (__expf(vy) - 1.f);
    hout[(size_t)n * 64 + h * 16 + l16] = pack_bf2(vx, vy);
}

// ---------------- final classifier: one wave per node ----------------
__global__ __launch_bounds__(256, 8) void classifier_kernel(
        const uint_t* __restrict__ h16, const float* __restrict__ cW,
        const float* __restrict__ cb, float* __restrict__ fout, int N){
    int n = blockIdx.x * 4 + (threadIdx.x >> 6);
    int l = threadIdx.x & 63;
    if (n >= N) return;
    uint_t u = h16[(size_t)n * 64 + l];
    float2 cw2 = ((const float2*)cW)[l];
    float p = bflo(u) * cw2.x + bfhi(u) * cw2.y;
    p = wsum(p);
    if (l == 0) fout[n] = 1.f / (1.f + __expf(-(p + cb[0])));
}

extern "C" void kernel_launch(void* const* d_in, const int* in_sizes, int n_in,
                              void* d_out, int out_size, void* d_ws, size_t ws_size,
                              hipStream_t stream){
    const float* x   = (const float*)d_in[0];
    const int*   ei  = (const int*)d_in[1];
    const float* W1  = (const float*)d_in[2];
    const float* as1 = (const float*)d_in[3];
    const float* ad1 = (const float*)d_in[4];
    const float* b1  = (const float*)d_in[5];
    const float* W2  = (const float*)d_in[6];
    const float* as2 = (const float*)d_in[7];
    const float* ad2 = (const float*)d_in[8];
    const float* b2  = (const float*)d_in[9];
    const float* W3  = (const float*)d_in[10];
    const float* as3 = (const float*)d_in[11];
    const float* ad3 = (const float*)d_in[12];
    const float* b3  = (const float*)d_in[13];
    const float* cW  = (const float*)d_in[14];
    const float* cb  = (const float*)d_in[15];
    float* out = (float*)d_out;

    int N = in_sizes[0] / 3;
    int E = in_sizes[1] / 2;
    int EN = E + N;
    int NBK = (N + BK_NODES - 1) / BK_NODES;

    char* ws = (char*)d_ws;
    size_t off = 0;
    auto alloc = [&](size_t bytes) -> void* {
        void* p = ws + off;
        off += (bytes + 255) & ~(size_t)255;
        return p;
    };
    int*    indptr  = (int*)alloc((size_t)N * 4);
    int*    indend  = (int*)alloc((size_t)N * 4);
    int*    srcs    = (int*)alloc((size_t)NBK * SLAB * 4);
    uint_t* pairbuf = (uint_t*)alloc((size_t)NBK * SLAB * 4);
    uint_t* XP      = (uint_t*)alloc((size_t)N * 64 * 4);   // packed bf16x2
    uint_t* H16     = (uint_t*)alloc((size_t)N * 64 * 4);   // packed bf16x2
    float*  ALS     = (float*)alloc((size_t)N * 4 * 4);
    float*  ALD     = (float*)alloc((size_t)N * 4 * 4);
    int*    gcursor = (int*)alloc((size_t)MAXBK * 4);
    uint_t* BP2     = (uint_t*)alloc((size_t)8192 * 4);
    uint_t* BP3     = (uint_t*)alloc((size_t)8192 * 4);
    (void)ws_size;

    int pb = (EN + PART_CHUNK - 1) / PART_CHUNK;

    wpack_zero<<<64, 256, 0, stream>>>(W2, W3, BP2, BP3, gcursor);
    partition_slab<<<pb, 256, 0, stream>>>(ei, E, N, gcursor, pairbuf, NBK);
    sort2_slab<<<NBK, 256, 0, stream>>>(pairbuf, gcursor, indptr, indend, srcs, N, NBK);

    int chunks = (N + 15) / 16;
    int a5 = ((chunks + 1) / 2) * 8;              // head-split agg grid
    int gb = ((N + 15) / 16 + 3) / 4;
    // layer 1 (K=3)
    linear_al<<<(N + 7) / 8, 128, 0, stream>>>(x, W1, as1, ad1, XP, ALS, ALD, N, 3);
    gat_agg5<<<a5, 256, 0, stream>>>(XP, ALS, ALD, indptr, indend, srcs, b1, H16, N);
    // layer 2 (MFMA)
    gemm_mfma<<<gb, 256, 0, stream>>>(H16, BP2, as2, ad2, XP, ALS, ALD, N);
    gat_agg5<<<a5, 256, 0, stream>>>(XP, ALS, ALD, indptr, indend, srcs, b2, H16, N);
    // layer 3 (MFMA) + separate classifier
    gemm_mfma<<<gb, 256, 0, stream>>>(H16, BP3, as3, ad3, XP, ALS, ALD, N);
    gat_agg5<<<a5, 256, 0, stream>>>(XP, ALS, ALD, indptr, indend, srcs, b3, H16, N);
    classifier_kernel<<<(N + 3) / 4, 256, 0, stream>>>(H16, cW, cb, out, N);
}

// Round 14
// 206.396 us; speedup vs baseline: 1.7202x; 1.7202x over previous
//
#include <hip/hip_runtime.h>
#include <math.h>

typedef unsigned int uint_t;
typedef __attribute__((ext_vector_type(8))) short bf16x8;
typedef __attribute__((ext_vector_type(4))) float f32x4;

#define BK_SHIFT 7
#define BK_NODES 128
#define MAXBK 512          // supports N <= 65536
#define PART_CHUNK 4096
#define SLAB 4096          // per-bucket slab capacity (lambda~2200, 40 sigma headroom)

__device__ __forceinline__ float lrelu(float x){ return x > 0.f ? x : 0.2f*x; }
__device__ __forceinline__ float sel4(float a, float b, float c, float d, int h){
    return h==0 ? a : (h==1 ? b : (h==2 ? c : d));
}
__device__ __forceinline__ float wsum(float v){
    #pragma unroll
    for (int m = 1; m < 64; m <<= 1) v += __shfl_xor(v, m);
    return v;
}
__device__ __forceinline__ uint_t pack_bf2(float a, float b){
    uint_t ua = __float_as_uint(a); uint_t ub = __float_as_uint(b);
    ua += 0x7FFFu + ((ua >> 16) & 1u);
    ub += 0x7FFFu + ((ub >> 16) & 1u);
    return (ua >> 16) | (ub & 0xFFFF0000u);
}
__device__ __forceinline__ float bflo(uint_t u){ return __uint_as_float(u << 16); }
__device__ __forceinline__ float bfhi(uint_t u){ return __uint_as_float(u & 0xFFFF0000u); }
__device__ __forceinline__ bf16x8 mk_bf8(uint4 u){
    bf16x8 r;
    r[0]=(short)(u.x & 0xFFFFu); r[1]=(short)(u.x >> 16);
    r[2]=(short)(u.y & 0xFFFFu); r[3]=(short)(u.y >> 16);
    r[4]=(short)(u.z & 0xFFFFu); r[5]=(short)(u.z >> 16);
    r[6]=(short)(u.w & 0xFFFFu); r[7]=(short)(u.w >> 16);
    return r;
}

// ---------------- W pre-pack + gcursor zero (launched FIRST) ----------------
// Bpack uint index: cb*1024 + kb*256 + kg*64 + c*4 + u -> bf16 pair k=kb*32+kg*8+2u, col=cb*16+c
__global__ __launch_bounds__(256) void wpack_zero(
        const float* __restrict__ W2, const float* __restrict__ W3,
        uint_t* __restrict__ B2, uint_t* __restrict__ B3,
        int* __restrict__ gcursor){
    int idx = blockIdx.x * 256 + threadIdx.x;      // 0..16383
    if (idx < MAXBK) gcursor[idx] = 0;
    const float* W = (idx < 8192) ? W2 : W3;
    uint_t* Bp = (idx < 8192) ? B2 : B3;
    int i = idx & 8191;
    int u = i & 3, c = (i >> 2) & 15, kg = (i >> 6) & 3, kb = (i >> 8) & 3, cb = (i >> 10) & 7;
    int k = kb * 32 + kg * 8 + 2 * u;
    int col = cb * 16 + c;
    Bp[i] = pack_bf2(W[k * 128 + col], W[(k + 1) * 128 + col]);
}

// ---------------- CSR build (slab) ----------------

// partition packed (src | dlow<<25) into per-bucket slab regions; single ei pass
__global__ __launch_bounds__(256) void partition_slab(
        const int* __restrict__ ei, int E, int N,
        int* __restrict__ gcursor, uint_t* __restrict__ pairbuf, int NBK){
    __shared__ int hist[MAXBK];
    __shared__ int sA[MAXBK];
    __shared__ int destadj[MAXBK];
    __shared__ int cnt2[MAXBK];
    __shared__ uint_t staged[PART_CHUNK];
    __shared__ unsigned short sbk[PART_CHUNK];
    int t = threadIdx.x;
    int base = blockIdx.x * PART_CHUNK;
    int total = E + N;
    int cnt = total - base; if (cnt > PART_CHUNK) cnt = PART_CHUNK; if (cnt < 0) cnt = 0;

    // read this block's edges once, into registers (static-indexed -> VGPRs)
    int sreg[16], dreg[16];
    #pragma unroll
    for (int q = 0; q < 16; ++q){
        int i = t + q * 256;
        int idx = base + i;
        int s = 0, d = -1;
        if (i < cnt){
            if (idx < E){ s = ei[idx]; d = ei[E + idx]; }
            else        { s = d = idx - E; }
        }
        sreg[q] = s; dreg[q] = d;
    }

    for (int i = t; i < MAXBK; i += 256){ hist[i] = 0; cnt2[i] = 0; }
    __syncthreads();
    #pragma unroll
    for (int q = 0; q < 16; ++q)
        if (dreg[q] >= 0) atomicAdd(&hist[dreg[q] >> BK_SHIFT], 1);
    __syncthreads();
    sA[t] = hist[t]; sA[t + 256] = hist[t + 256];
    __syncthreads();
    for (int off = 1; off < MAXBK; off <<= 1){
        int i0 = t, i1 = t + 256;
        int a0 = sA[i0] + ((i0 >= off) ? sA[i0 - off] : 0);
        int a1 = sA[i1] + ((i1 >= off) ? sA[i1 - off] : 0);
        __syncthreads();
        sA[i0] = a0; sA[i1] = a1;
        __syncthreads();
    }
    for (int b = t; b < NBK; b += 256){
        int c = hist[b];
        int gstart = (b == 0) ? 0 : sA[b - 1];
        int rbase = c > 0 ? atomicAdd(&gcursor[b], c) : 0;
        destadj[b] = b * SLAB + rbase - gstart;
        cnt2[b] = gstart;
    }
    __syncthreads();
    #pragma unroll
    for (int q = 0; q < 16; ++q){
        if (dreg[q] >= 0){
            int b = dreg[q] >> BK_SHIFT;
            int pos = atomicAdd(&cnt2[b], 1);
            staged[pos] = (uint_t)sreg[q] | ((uint_t)(dreg[q] & (BK_NODES - 1)) << 25);
            sbk[pos] = (unsigned short)b;
        }
    }
    __syncthreads();
    for (int p = t; p < cnt; p += 256){
        int b = (int)sbk[p];
        pairbuf[destadj[b] + p] = staged[p];
    }
}

// per-bucket counting sort inside the slab; derives indptr/indend
__global__ __launch_bounds__(256) void sort2_slab(
        const uint_t* __restrict__ pairbuf, const int* __restrict__ gcursor,
        int* __restrict__ indptr, int* __restrict__ indend,
        int* __restrict__ srcs, int N, int NBK){
    int b = blockIdx.x;
    int cnt = gcursor[b];
    int base = b * SLAB;
    int nb = b << BK_SHIFT;
    __shared__ int nh[BK_NODES];
    __shared__ int noff[BK_NODES];
    __shared__ int outb[SLAB];
    int t = threadIdx.x;
    if (t < BK_NODES) nh[t] = 0;
    __syncthreads();
    for (int i = t; i < cnt; i += 256){
        uint_t pr = pairbuf[base + i];
        atomicAdd(&nh[(int)(pr >> 25)], 1);
    }
    __syncthreads();
    if (t < BK_NODES) noff[t] = nh[t];
    __syncthreads();
    for (int off = 1; off < BK_NODES; off <<= 1){
        int u = 0;
        if (t < BK_NODES && t >= off) u = noff[t - off];
        __syncthreads();
        if (t < BK_NODES) noff[t] += u;
        __syncthreads();
    }
    if (t < BK_NODES){
        int node = nb + t;
        if (node < N){
            int excl = noff[t] - nh[t];
            indptr[node] = base + excl;
            indend[node] = base + noff[t];
        }
        nh[t] = noff[t] - nh[t];      // reuse as local cursor
    }
    __syncthreads();
    for (int i = t; i < cnt; i += 256){
        uint_t pr = pairbuf[base + i];
        int pos = atomicAdd(&nh[(int)(pr >> 25)], 1);
        outb[pos] = (int)(pr & 0x1FFFFFFu);
    }
    __syncthreads();
    for (int i = t; i < cnt; i += 256) srcs[base + i] = outb[i];
}

// ---------------- layer-1 linear (K=3): xp packed bf16x2 ----------------
__global__ __launch_bounds__(128) void linear_al(
        const float* __restrict__ in, const float* __restrict__ W,
        const float* __restrict__ as_, const float* __restrict__ ad_,
        uint_t* __restrict__ xp16, float* __restrict__ als, float* __restrict__ ald,
        int N, int K){
    __shared__ float hs[8 * 3];
    int t = threadIdx.x;
    int base = blockIdx.x * 8;
    int rows = N - base; if (rows > 8) rows = 8;
    for (int idx = t; idx < rows * K; idx += 128){
        int r = idx / K, k = idx - r * K;
        hs[r * K + k] = in[(size_t)(base + r) * K + k];
    }
    __syncthreads();
    float acc[8] = {0.f,0.f,0.f,0.f,0.f,0.f,0.f,0.f};
    for (int k = 0; k < K; ++k){
        float w = W[k * 128 + t];
        #pragma unroll
        for (int r = 0; r < 8; ++r) acc[r] += hs[r * K + k] * w;
    }
    float asv = as_[t], adv = ad_[t];
    for (int r = 0; r < rows; ++r){
        int row = base + r;
        float v = acc[r];
        float vo = __shfl_xor(v, 1);
        if (!(t & 1)) xp16[(size_t)row * 64 + (t >> 1)] = pack_bf2(v, vo);
        float vs = v * asv, vd = v * adv;
        #pragma unroll
        for (int m = 16; m >= 1; m >>= 1){
            vs += __shfl_xor(vs, m);
            vd += __shfl_xor(vd, m);
        }
        if ((t & 31) == 0){
            int h = t >> 5;
            als[row * 4 + h] = vs;
            ald[row * 4 + h] = vd;
        }
    }
}

// ---------------- K=128 linear via MFMA bf16; B staged in LDS per block ----------------
__global__ __launch_bounds__(256) void gemm_mfma(
        const uint_t* __restrict__ h16, const uint_t* __restrict__ bpack,
        const float* __restrict__ as_, const float* __restrict__ ad_,
        uint_t* __restrict__ xp16, float* __restrict__ als, float* __restrict__ ald,
        int N){
    __shared__ uint4 Bs[2048];         // 32 KB: full B-fragment table, shared by 4 waves
    int t = threadIdx.x;
    const uint4* bp4 = (const uint4*)bpack;
    #pragma unroll
    for (int q = 0; q < 8; ++q) Bs[t + q * 256] = bp4[t + q * 256];
    __syncthreads();                   // single barrier, before any early-return

    int w = threadIdx.x >> 6;
    int l = threadIdx.x & 63;
    int stripe = blockIdx.x * 4 + w;
    int base = stripe * 16;
    if (base >= N) return;
    int r16 = l & 15;
    int kg  = l >> 4;
    int row = base + r16;
    int rowc = row < N ? row : N - 1;

    bf16x8 afr[4];
    const uint4* hrow = (const uint4*)(h16 + (size_t)rowc * 64);
    #pragma unroll
    for (int kb = 0; kb < 4; ++kb) afr[kb] = mk_bf8(hrow[kb * 4 + kg]);

    f32x4 acc[8];
    #pragma unroll
    for (int cb = 0; cb < 8; ++cb) acc[cb] = (f32x4){0.f, 0.f, 0.f, 0.f};

    #pragma unroll
    for (int cb = 0; cb < 8; ++cb){
        #pragma unroll
        for (int kb = 0; kb < 4; ++kb){
            bf16x8 bfr = mk_bf8(Bs[((cb * 4 + kb) * 4 + kg) * 16 + r16]);
            acc[cb] = __builtin_amdgcn_mfma_f32_16x16x32_bf16(afr[kb], bfr, acc[cb], 0, 0, 0);
        }
    }

    #pragma unroll
    for (int reg = 0; reg < 4; ++reg){
        int ro = base + kg * 4 + reg;
        bool wr = (ro < N) && ((r16 & 1) == 0);
        #pragma unroll
        for (int cb = 0; cb < 8; ++cb){
            float v  = acc[cb][reg];
            float vo = __shfl_xor(v, 1);
            if (wr) xp16[(size_t)ro * 64 + cb * 8 + (r16 >> 1)] = pack_bf2(v, vo);
        }
        #pragma unroll
        for (int h = 0; h < 4; ++h){
            float a0 = as_[h * 32 + r16],      a1 = as_[h * 32 + 16 + r16];
            float g0 = ad_[h * 32 + r16],      g1 = ad_[h * 32 + 16 + r16];
            float ps = acc[2 * h][reg] * a0 + acc[2 * h + 1][reg] * a1;
            float pd = acc[2 * h][reg] * g0 + acc[2 * h + 1][reg] * g1;
            ps += __shfl_xor(ps, 1); ps += __shfl_xor(ps, 2);
            ps += __shfl_xor(ps, 4); ps += __shfl_xor(ps, 8);
            pd += __shfl_xor(pd, 1); pd += __shfl_xor(pd, 2);
            pd += __shfl_xor(pd, 4); pd += __shfl_xor(pd, 8);
            if (r16 == 0 && ro < N){
                als[(size_t)ro * 4 + h] = ps;
                ald[(size_t)ro * 4 + h] = pd;
            }
        }
    }
}

// ---------------- per-node softmax aggregation: one WAVE per node ----------------
// lane l owns channels 2l,2l+1 (head h=l>>4). ssh int + esh float4 staging
// (esh[j][h]: 4 head-values in 16 consecutive bytes -> conflict-free).
__global__ __launch_bounds__(256, 8) void gat_agg4(
        const uint_t* __restrict__ xp16, const float4* __restrict__ als,
        const float4* __restrict__ ald,
        const int* __restrict__ indptr, const int* __restrict__ indend,
        const int* __restrict__ srcs,
        const float* __restrict__ bias,
        uint_t* __restrict__ hout, int N, int mode,
        const float* __restrict__ cW, const float* __restrict__ cb,
        float* __restrict__ fout){
    int wid = threadIdx.x >> 6;
    int l   = threadIdx.x & 63;
    int n = blockIdx.x * 4 + wid;
    __shared__ int   ssh[4][64];
    __shared__ float esh[4][64][4];
    if (n >= N) return;

    int beg = indptr[n], end = indend[n];
    float4 ad4 = ald[n];
    int h = l >> 4;

    float d0 = 0.f, d1 = 0.f, d2 = 0.f, d3 = 0.f;
    float ax = 0.f, ay = 0.f;

    for (int cbeg = beg; cbeg < end; cbeg += 64){
        int cnt = end - cbeg; if (cnt > 64) cnt = 64;
        if (l < cnt){
            int s = srcs[cbeg + l];
            ssh[wid][l] = s;
            float4 a4 = als[s];
            float p0 = __expf(lrelu(a4.x + ad4.x));
            float p1 = __expf(lrelu(a4.y + ad4.y));
            float p2 = __expf(lrelu(a4.z + ad4.z));
            float p3 = __expf(lrelu(a4.w + ad4.w));
            *((float4*)&esh[wid][l][0]) = make_float4(p0, p1, p2, p3);
            d0 += p0; d1 += p1; d2 += p2; d3 += p3;
        }
        __builtin_amdgcn_wave_barrier();

        int j = 0;
        for (; j + 16 <= cnt; j += 16){
            int ss[16]; float ww[16]; uint_t uu[16];
            #pragma unroll
            for (int q = 0; q < 16; ++q){ ss[q] = ssh[wid][j+q]; ww[q] = esh[wid][j+q][h]; }
            #pragma unroll
            for (int q = 0; q < 16; ++q) uu[q] = xp16[(size_t)ss[q] * 64 + l];
            #pragma unroll
            for (int q = 0; q < 16; ++q){
                ax = fmaf(bflo(uu[q]), ww[q], ax);
                ay = fmaf(bfhi(uu[q]), ww[q], ay);
            }
        }
        for (; j + 8 <= cnt; j += 8){
            int ss[8]; float ww[8]; uint_t uu[8];
            #pragma unroll
            for (int q = 0; q < 8; ++q){ ss[q] = ssh[wid][j+q]; ww[q] = esh[wid][j+q][h]; }
            #pragma unroll
            for (int q = 0; q < 8; ++q) uu[q] = xp16[(size_t)ss[q] * 64 + l];
            #pragma unroll
            for (int q = 0; q < 8; ++q){
                ax = fmaf(bflo(uu[q]), ww[q], ax);
                ay = fmaf(bfhi(uu[q]), ww[q], ay);
            }
        }
        for (; j < cnt; ++j){
            int s = ssh[wid][j];
            float w = esh[wid][j][h];
            uint_t u = xp16[(size_t)s * 64 + l];
            ax = fmaf(bflo(u), w, ax);
            ay = fmaf(bfhi(u), w, ay);
        }
    }

    d0 = wsum(d0); d1 = wsum(d1); d2 = wsum(d2); d3 = wsum(d3);

    float dh = sel4(d0, d1, d2, d3, h);
    float inv = 1.f / (dh + 1e-16f);
    float2 b2 = ((const float2*)bias)[l];
    float vx = ax * inv + b2.x;
    float vy = ay * inv + b2.y;
    vx = vx > 0.f ? vx : (__expf(vx) - 1.f);
    vy = vy > 0.f ? vy : (__expf(vy) - 1.f);

    if (mode == 0){
        hout[(size_t)n * 64 + l] = pack_bf2(vx, vy);
    } else {
        float2 cw2 = ((const float2*)cW)[l];
        float p = vx * cw2.x + vy * cw2.y;
        p = wsum(p);
        if (l == 0){
            float logit = p + cb[0];
            fout[n] = 1.f / (1.f + __expf(-logit));
        }
    }
}

extern "C" void kernel_launch(void* const* d_in, const int* in_sizes, int n_in,
                              void* d_out, int out_size, void* d_ws, size_t ws_size,
                              hipStream_t stream){
    const float* x   = (const float*)d_in[0];
    const int*   ei  = (const int*)d_in[1];
    const float* W1  = (const float*)d_in[2];
    const float* as1 = (const float*)d_in[3];
    const float* ad1 = (const float*)d_in[4];
    const float* b1  = (const float*)d_in[5];
    const float* W2  = (const float*)d_in[6];
    const float* as2 = (const float*)d_in[7];
    const float* ad2 = (const float*)d_in[8];
    const float* b2  = (const float*)d_in[9];
    const float* W3  = (const float*)d_in[10];
    const float* as3 = (const float*)d_in[11];
    const float* ad3 = (const float*)d_in[12];
    const float* b3  = (const float*)d_in[13];
    const float* cW  = (const float*)d_in[14];
    const float* cb  = (const float*)d_in[15];
    float* out = (float*)d_out;

    int N = in_sizes[0] / 3;
    int E = in_sizes[1] / 2;
    int EN = E + N;
    int NBK = (N + BK_NODES - 1) / BK_NODES;

    char* ws = (char*)d_ws;
    size_t off = 0;
    auto alloc = [&](size_t bytes) -> void* {
        void* p = ws + off;
        off += (bytes + 255) & ~(size_t)255;
        return p;
    };
    int*    indptr  = (int*)alloc((size_t)N * 4);
    int*    indend  = (int*)alloc((size_t)N * 4);
    int*    srcs    = (int*)alloc((size_t)NBK * SLAB * 4);
    uint_t* pairbuf = (uint_t*)alloc((size_t)NBK * SLAB * 4);
    uint_t* XP      = (uint_t*)alloc((size_t)N * 64 * 4);   // packed bf16x2
    uint_t* H16     = (uint_t*)alloc((size_t)N * 64 * 4);   // packed bf16x2
    float*  ALS     = (float*)alloc((size_t)N * 4 * 4);
    float*  ALD     = (float*)alloc((size_t)N * 4 * 4);
    int*    gcursor = (int*)alloc((size_t)MAXBK * 4);
    uint_t* BP2     = (uint_t*)alloc((size_t)8192 * 4);
    uint_t* BP3     = (uint_t*)alloc((size_t)8192 * 4);
    (void)ws_size;

    int pb = (EN + PART_CHUNK - 1) / PART_CHUNK;

    wpack_zero<<<64, 256, 0, stream>>>(W2, W3, BP2, BP3, gcursor);
    partition_slab<<<pb, 256, 0, stream>>>(ei, E, N, gcursor, pairbuf, NBK);
    sort2_slab<<<NBK, 256, 0, stream>>>(pairbuf, gcursor, indptr, indend, srcs, N, NBK);

    int ab = (N + 3) / 4;
    int gb = ((N + 15) / 16 + 3) / 4;
    // layer 1 (K=3)
    linear_al<<<(N + 7) / 8, 128, 0, stream>>>(x, W1, as1, ad1, XP, ALS, ALD, N, 3);
    gat_agg4<<<ab, 256, 0, stream>>>(XP, (const float4*)ALS, (const float4*)ALD,
                                     indptr, indend, srcs, b1, H16, N, 0, nullptr, nullptr, nullptr);
    // layer 2 (MFMA)
    gemm_mfma<<<gb, 256, 0, stream>>>(H16, BP2, as2, ad2, XP, ALS, ALD, N);
    gat_agg4<<<ab, 256, 0, stream>>>(XP, (const float4*)ALS, (const float4*)ALD,
                                     indptr, indend, srcs, b2, H16, N, 0, nullptr, nullptr, nullptr);
    // layer 3 (MFMA) + fused classifier
    gemm_mfma<<<gb, 256, 0, stream>>>(H16, BP3, as3, ad3, XP, ALS, ALD, N);
    gat_agg4<<<ab, 256, 0, stream>>>(XP, (const float4*)ALS, (const float4*)ALD,
                                     indptr, indend, srcs, b3, nullptr, N, 1, cW, cb, out);
}